// Round 22
// baseline (293.995 us; speedup 1.0000x reference)
//
#include <hip/hip_runtime.h>

// ---------------------------------------------------------------------------
// MambaLatentBiMap: 2 branches (fwd / reversed) x 2 mamba layers + gates.
// Rows r = (j, b, l). Layer index for stage s, branch j: lidx = s + 2*j.
// MFMA GEMMs: EXACT 3-way bf16 split (6 product terms -> fp32-equivalent),
// operands pre-split into 3 u16 planes; global_load_lds staging; PRE-SWIZZLED
// global plane layout (swzi) for conflict-free ds_read_b128.
// Round-22: (1) GEMM1 K-split x2 -> 512 blocks = 2 blocks/CU (pipelined
// staging now covers latency cross-block; r15's pre-pipeline attempt was
// confounded by gate x4): consumers sum the two partial planes inline
// (gemm23 UZt loader: u0+u1 before the conv fma; scan z loader: z0+z1).
// (2) combine2<1> dispatch dropped: gate partials live in PGATE and the
// FINAL combine computes sigmoid(p0+p1+bg) inline (GATE round-trip gone).
// Rest = r21 best (286.9us): 2-deep pipelined gemm_mfma (counted vmcnt(12)),
// conv fused into gemm23, gate/GEMM4 K-split x2, scan state-split thread
// pairs (16 states/thread, 1024 blocks), s1 combine folded into final.
// ---------------------------------------------------------------------------

#define LSEQ 1024
#define SCAN_CL 16
#define SCAN_NC 64
#define G1PLANE 2097152L   // 4096*512 floats per GEMM1 partial plane

#if __has_builtin(__builtin_amdgcn_exp2f)
#define EXP2(x) __builtin_amdgcn_exp2f(x)
#else
#define EXP2(x) exp2f(x)
#endif

typedef short bf16x8 __attribute__((ext_vector_type(8)));
typedef float f32x4 __attribute__((ext_vector_type(4)));

__device__ __forceinline__ float sigmoidf_(float x) { return 1.f / (1.f + __expf(-x)); }
__device__ __forceinline__ float siluf_(float x)    { return x / (1.f + __expf(-x)); }
__device__ __forceinline__ float softplusf_(float x){ return x > 20.f ? x : log1pf(__expf(x)); }

__device__ __forceinline__ unsigned short bf16rne_(float v) {
  unsigned u = __float_as_uint(v);
  return (unsigned short)((u + 0x7FFFu + ((u >> 16) & 1u)) >> 16);
}
__device__ __forceinline__ float bfto_(unsigned short h) {
  return __uint_as_float(((unsigned)h) << 16);
}
__device__ __forceinline__ void split3_(float v, unsigned short& h,
                                        unsigned short& m, unsigned short& l) {
  h = bf16rne_(v); float r = v - bfto_(h);
  m = bf16rne_(r); float r2 = r - bfto_(m);
  l = bf16rne_(r2);
}

// swizzle: XOR k-bits 3-4 of a u16 plane index with row bits 1-2 (involution;
// valid since every plane K-dim is a multiple of 32).
__device__ __forceinline__ long swzi(long idx, long row) {
  return idx ^ (((row >> 1) & 3) << 3);
}

// ---------------- fused preprocessing (1 dispatch) -------------------------
__device__ void tconv3_body(const float* __restrict__ in,
                            unsigned short* __restrict__ oh,
                            unsigned short* __restrict__ om,
                            unsigned short* __restrict__ ol,
                            int K, int N, int bx, int by, int z) {
  __shared__ float T[32][33];
  int n0 = bx * 32, k0 = by * 32;
  int tx = threadIdx.x & 31, ty = threadIdx.x >> 5;   // 32 x 8
  const float* src = in + (long)z * K * N;
#pragma unroll
  for (int m = 0; m < 4; ++m)
    T[ty + 8 * m][tx] = src[(long)(k0 + ty + 8 * m) * N + n0 + tx];
  __syncthreads();
  long obase = (long)z * N * K;
#pragma unroll
  for (int m = 0; m < 4; ++m) {
    float v = T[tx][ty + 8 * m];
    int n = n0 + ty + 8 * m;
    long o = swzi(obase + (long)n * K + k0 + tx, n);
    split3_(v, oh[o], om[o], ol[o]);
  }
}

__device__ void split3v_body(const float4* __restrict__ in,
                             unsigned short* __restrict__ oh,
                             unsigned short* __restrict__ om,
                             unsigned short* __restrict__ ol, int i) {
  float4 v = in[i];
  long b = 4L * i;                     // u16 base index; row = b >> 10 (K=1024)
  long sb = swzi(b, b >> 10);
  ushort4 H, M, L;
  split3_(v.x, H.x, M.x, L.x); split3_(v.y, H.y, M.y, L.y);
  split3_(v.z, H.z, M.z, L.z); split3_(v.w, H.w, M.w, L.w);
  *(ushort4*)(oh + sb) = H; *(ushort4*)(om + sb) = M; *(ushort4*)(ol + sb) = L;
}

__global__ __launch_bounds__(256)
void preprocess_kernel(const float* __restrict__ x, const float* __restrict__ Wg,
                       const float* __restrict__ Win, const float* __restrict__ Wout,
                       const float* __restrict__ Alog,
                       unsigned short* __restrict__ Xh, unsigned short* __restrict__ Xm,
                       unsigned short* __restrict__ Xl,
                       unsigned short* __restrict__ XGh, unsigned short* __restrict__ XGm,
                       unsigned short* __restrict__ XGl,
                       unsigned short* __restrict__ Wgh, unsigned short* __restrict__ Wgm,
                       unsigned short* __restrict__ Wgl,
                       unsigned short* __restrict__ WinTh, unsigned short* __restrict__ WinTm,
                       unsigned short* __restrict__ WinTl,
                       unsigned short* __restrict__ WoutTh, unsigned short* __restrict__ WoutTm,
                       unsigned short* __restrict__ WoutTl,
                       float* __restrict__ Aneg) {
  const int bid = blockIdx.x;
  if (bid < 8192) {                       // prep: x (B,D,L) -> X planes
    long idx = (long)bid * 256 + threadIdx.x;
    int d = (int)(idx & 255);
    long t = idx >> 8;
    int l = (int)(t & 1023);
    int t2 = (int)(t >> 10);
    int b = t2 & 3;
    int j = t2 >> 2;
    int lsrc = j ? (1023 - l) : l;
    float v = x[((long)(b * 256 + d)) * LSEQ + lsrc];
    long o = swzi(idx, t);
    split3_(v, Xh[o], Xm[o], Xl[o]);
  } else if (bid < 9216) {                // split x -> XG planes (K=1024)
    int i = (bid - 8192) * 256 + threadIdx.x;
    split3v_body((const float4*)x, XGh, XGm, XGl, i);
  } else if (bid < 11264) {               // split Wg -> planes (K=1024)
    int i = (bid - 9216) * 256 + threadIdx.x;
    split3v_body((const float4*)Wg, Wgh, Wgm, Wgl, i);
  } else if (bid < 11776) {               // tconv3 Win (K=256,N=512, z=4)
    int t = bid - 11264;                  // dim3(16,8,4)
    tconv3_body(Win, WinTh, WinTm, WinTl, 256, 512, t & 15, (t >> 4) & 7, t >> 7);
  } else if (bid < 12032) {               // tconv3 Wout (K=256,N=256, z=4)
    int t = bid - 11776;                  // dim3(8,8,4)
    tconv3_body(Wout, WoutTh, WoutTm, WoutTl, 256, 256, t & 7, (t >> 3) & 7, t >> 6);
  } else {                                // aneg: -exp(Alog)*log2(e)
    int idx = (bid - 12032) * 256 + threadIdx.x;   // 32768
    Aneg[idx] = -__expf(Alog[idx]) * 1.4426950408889634f;
  }
}

// ---------------- MFMA 3-split bf16 GEMM (2-deep pipelined staging) --------
__device__ __forceinline__ void gload16(const unsigned short* g, unsigned short* l) {
  __builtin_amdgcn_global_load_lds(
      (const __attribute__((address_space(1))) unsigned int*)g,
      (__attribute__((address_space(3))) unsigned int*)l, 16, 0, 0);
}

template <int KSPLIT>
__global__ __launch_bounds__(256)
void gemm_mfma(const unsigned short* __restrict__ Ah_g,
               const unsigned short* __restrict__ Am_g,
               const unsigned short* __restrict__ Al_g, long aZ, int lda,
               const unsigned short* __restrict__ Bh_g,
               const unsigned short* __restrict__ Bm_g,
               const unsigned short* __restrict__ Bl_g, long bZ, int ldb,
               float* __restrict__ C, long cZ, int N, int KH) {
  __shared__ unsigned short S[2][6][128 * 32];   // double-buffered, 96 KB
  const int bz = blockIdx.z;
  const int z  = (KSPLIT == 2) ? (bz >> 1) : bz;
  const int kh = (KSPLIT == 2) ? (bz & 1) : 0;
  const int m0 = blockIdx.y * 128, n0 = blockIdx.x * 128;
  const int tid = threadIdx.x;

  const long khoff = (long)kh * KH;
  const long a0 = (long)z * aZ + (long)(m0 + (tid >> 2)) * lda + khoff + (tid & 3) * 8;
  const long a1 = a0 + 64L * lda;
  const long b0 = (long)z * bZ + (long)(n0 + (tid >> 2)) * ldb + khoff + (tid & 3) * 8;
  const long b1 = b0 + 64L * ldb;
  const int l0 = tid * 8, l1 = tid * 8 + 2048;   // u16 offsets into S[b][p]

  const int lane = tid & 63, w = tid >> 6;
  const int wr = w >> 1, wc = w & 1;
  const int fr = lane & 15, g = lane >> 4;

  f32x4 acc[4][4];
#pragma unroll
  for (int i = 0; i < 4; ++i)
#pragma unroll
    for (int j = 0; j < 4; ++j)
#pragma unroll
      for (int q = 0; q < 4; ++q) acc[i][j][q] = 0.f;

#define ISSUE_TILE(B, KOFF)                                 \
  do {                                                      \
    gload16(Ah_g + a0 + (KOFF), &S[B][0][l0]);              \
    gload16(Ah_g + a1 + (KOFF), &S[B][0][l1]);              \
    gload16(Am_g + a0 + (KOFF), &S[B][1][l0]);              \
    gload16(Am_g + a1 + (KOFF), &S[B][1][l1]);              \
    gload16(Al_g + a0 + (KOFF), &S[B][2][l0]);              \
    gload16(Al_g + a1 + (KOFF), &S[B][2][l1]);              \
    gload16(Bh_g + b0 + (KOFF), &S[B][3][l0]);              \
    gload16(Bh_g + b1 + (KOFF), &S[B][3][l1]);              \
    gload16(Bm_g + b0 + (KOFF), &S[B][4][l0]);              \
    gload16(Bm_g + b1 + (KOFF), &S[B][4][l1]);              \
    gload16(Bl_g + b0 + (KOFF), &S[B][5][l0]);              \
    gload16(Bl_g + b1 + (KOFF), &S[B][5][l1]);              \
  } while (0)

  ISSUE_TILE(0, 0);                      // prologue: tile 0 in flight
  int cur = 0;

  for (int k0 = 0; k0 < KH; k0 += 32) {
    asm volatile("s_waitcnt lgkmcnt(0)" ::: "memory");
    __builtin_amdgcn_s_barrier();
    if (k0 + 32 < KH) {
      ISSUE_TILE(cur ^ 1, k0 + 32);      // next tile into the free buffer
      asm volatile("s_waitcnt vmcnt(12)" ::: "memory");  // cur's 12 done
    } else {
      asm volatile("s_waitcnt vmcnt(0)" ::: "memory");   // drain last tile
    }
    __builtin_amdgcn_s_barrier();        // cur buffer visible everywhere
    __builtin_amdgcn_sched_barrier(0);

    bf16x8 fb[3][4];
#pragma unroll
    for (int nf = 0; nf < 4; ++nf) {
      int rb = wc * 64 + nf * 16 + fr;
      int ob = rb * 32 + ((g ^ ((rb >> 1) & 3)) << 3);
      fb[0][nf] = *(const bf16x8*)&S[cur][3][ob];
      fb[1][nf] = *(const bf16x8*)&S[cur][4][ob];
      fb[2][nf] = *(const bf16x8*)&S[cur][5][ob];
    }
#pragma unroll
    for (int mf = 0; mf < 4; ++mf) {
      int ra = wr * 64 + mf * 16 + fr;
      int oa = ra * 32 + ((g ^ ((ra >> 1) & 3)) << 3);
      bf16x8 fah = *(const bf16x8*)&S[cur][0][oa];
      bf16x8 fam = *(const bf16x8*)&S[cur][1][oa];
      bf16x8 fal = *(const bf16x8*)&S[cur][2][oa];
#pragma unroll
      for (int nf = 0; nf < 4; ++nf) {
        acc[mf][nf] = __builtin_amdgcn_mfma_f32_16x16x32_bf16(fah, fb[0][nf], acc[mf][nf], 0, 0, 0);
        acc[mf][nf] = __builtin_amdgcn_mfma_f32_16x16x32_bf16(fah, fb[1][nf], acc[mf][nf], 0, 0, 0);
        acc[mf][nf] = __builtin_amdgcn_mfma_f32_16x16x32_bf16(fam, fb[0][nf], acc[mf][nf], 0, 0, 0);
        acc[mf][nf] = __builtin_amdgcn_mfma_f32_16x16x32_bf16(fam, fb[1][nf], acc[mf][nf], 0, 0, 0);
        acc[mf][nf] = __builtin_amdgcn_mfma_f32_16x16x32_bf16(fah, fb[2][nf], acc[mf][nf], 0, 0, 0);
        acc[mf][nf] = __builtin_amdgcn_mfma_f32_16x16x32_bf16(fal, fb[0][nf], acc[mf][nf], 0, 0, 0);
      }
    }
    cur ^= 1;
  }
#undef ISSUE_TILE

  float* Cz = C + (long)bz * cZ;
#pragma unroll
  for (int mf = 0; mf < 4; ++mf)
#pragma unroll
    for (int nf = 0; nf < 4; ++nf) {
      int col = n0 + wc * 64 + nf * 16 + fr;
      int row0 = m0 + wr * 64 + mf * 16 + g * 4;
#pragma unroll
      for (int q = 0; q < 4; ++q)
        Cz[(long)(row0 + q) * N + col] = acc[mf][nf][q];
    }
}

// ---------------- combine2: sum two K-split partial planes + epilogue ------
// OP 2: split3 -> swizzled planes (K=256)
template <int OP>
__global__ __launch_bounds__(256)
void combine2_kernel(const float* __restrict__ P, long pz,
                     float* __restrict__ outF,
                     unsigned short* __restrict__ oh,
                     unsigned short* __restrict__ om,
                     unsigned short* __restrict__ ol, long oz) {
  int z = blockIdx.y;
  long i = (long)blockIdx.x * 256 + threadIdx.x;
  float v = P[(long)(2 * z) * pz + i] + P[(long)(2 * z + 1) * pz + i];
  if (OP == 0) {
    outF[(long)z * oz + i] = v;
  } else {
    long o = (long)z * oz + swzi(i, i >> 8);   // row = i>>8, K = 256
    split3_(v, oh[o], om[o], ol[o]);
  }
}

// ---------------- fused CONV + GEMM2 + GEMM3 (BM=16, 512 blocks) -----------
// UZt loads sum the two GEMM1 K-split partial planes (u0+u1 before the conv
// fma == combine-then-use). Zero-pad at b-boundaries (l0==0) is bit-exact.
__global__ __launch_bounds__(256)
void gemm23_kernel(const float* __restrict__ PG1, const float* __restrict__ Wconv,
                   const float* __restrict__ bconv,
                   const float* __restrict__ Wxp,
                   const float* __restrict__ Wdt, const float* __restrict__ bdt,
                   float* __restrict__ UC, float* __restrict__ PROJ,
                   float* __restrict__ DTo, int stage) {
  __shared__ float UZt[19][256];   // u rows m0-3..m0+15 (partials summed)
  __shared__ float ucs[16][260];   // conv output (padded: bank-spread)
  __shared__ float Ws[16][80];
  __shared__ float PR[16][17];
  __shared__ float WD[16][256];
  const int z = blockIdx.y;
  const int lidx = stage + 2 * z;
  const int m0 = blockIdx.x * 16;                    // within 4096
  const int l0 = m0 & 1023;
  const float* W = Wxp + (long)lidx * 256 * 80;
  const int tid = threadIdx.x;
  const int tx = tid & 15, ty = tid >> 4;

#pragma unroll
  for (int t = 0; t < 16; ++t) {
    int e = t * 256 + tid;
    WD[e >> 8][e & 255] = Wdt[(long)lidx * 4096 + e];
  }

  {
    const long base = (long)(z * 2) * G1PLANE + ((long)(m0 - 3)) * 512 + tid;
#pragma unroll
    for (int r = 0; r < 19; ++r)
      UZt[r][tid] = (l0 == 0 && r < 3)
                        ? 0.f
                        : (PG1[base + (long)r * 512] +
                           PG1[base + G1PLANE + (long)r * 512]);
  }
  __syncthreads();

  {
    const float* wcp = Wconv + (long)(lidx * 256 + tid) * 4;
    float w0 = wcp[0], w1 = wcp[1], w2 = wcp[2], w3 = wcp[3];
    float bcv = bconv[lidx * 256 + tid];
#pragma unroll
    for (int it = 0; it < 16; ++it) {
      float acc = bcv;
      acc = fmaf(UZt[it + 0][tid], w0, acc);
      acc = fmaf(UZt[it + 1][tid], w1, acc);
      acc = fmaf(UZt[it + 2][tid], w2, acc);
      acc = fmaf(UZt[it + 3][tid], w3, acc);
      float ucv = acc * sigmoidf_(acc);
      UC[((long)z * 4096 + m0 + it) * 256 + tid] = ucv;
      ucs[it][tid] = ucv;
    }
  }
  __syncthreads();

  float acc[5];
#pragma unroll
  for (int j = 0; j < 5; ++j) acc[j] = 0.f;

  for (int k0 = 0; k0 < 256; k0 += 16) {
    {
      int k = tid >> 4, cg2 = (tid & 15) * 5;
#pragma unroll
      for (int i2 = 0; i2 < 5; ++i2)
        Ws[k][cg2 + i2] = W[(long)(k0 + k) * 80 + cg2 + i2];
    }
    __syncthreads();
#pragma unroll
    for (int kk = 0; kk < 16; ++kk) {
      float a = ucs[ty][k0 + kk];
#pragma unroll
      for (int j = 0; j < 5; ++j)
        acc[j] = fmaf(a, Ws[kk][tx * 5 + j], acc[j]);
    }
    __syncthreads();
  }

#pragma unroll
  for (int j = 0; j < 5; ++j) {
    int c = tx * 5 + j;
    float v = acc[j];
    PROJ[((long)z * 4096 + m0 + ty) * 80 + c] = v;
    if (c < 16) PR[ty][c] = v;
  }
  __syncthreads();

  for (int it = 0; it < 16; ++it) {
    float ssum = 0.f;
#pragma unroll
    for (int k = 0; k < 16; ++k) ssum = fmaf(PR[it][k], WD[k][tid], ssum);
    DTo[((long)z * 4096 + m0 + it) * 256 + tid] =
        softplusf_(ssum + bdt[lidx * 256 + tid]);
  }
}

// ---------------- selective scan: chunked, state-split thread pairs --------
// z values read as sum of the two GEMM1 partial planes.
template <int PASS>
__global__ __launch_bounds__(256)
void scan_chunk_kernel(const float* __restrict__ dt,
                       const float* __restrict__ uc,
                       const float* __restrict__ PG1,
                       const float* __restrict__ proj,
                       const float* __restrict__ Aneg,
                       const float* __restrict__ Dskip,
                       float* __restrict__ HST,   // [8][NC][256][32]
                       float* __restrict__ DTS,   // [8][NC][256]
                       unsigned short* __restrict__ YGh,
                       unsigned short* __restrict__ YGm,
                       unsigned short* __restrict__ YGl, int stage) {
  __shared__ __align__(16) float BC[SCAN_CL][64];
  const int blk = blockIdx.x;
  const int c128 = blk & 1;
  const int chunk = (blk >> 1) & (SCAN_NC - 1);
  const int jb = blk >> 7;
  const int tid = threadIdx.x;
  const int di = c128 * 128 + (tid >> 1);
  const int nh = tid & 1;
  const int j = jb >> 2;
  const int lidx = stage + 2 * j;
  const long r0 = (long)jb * 1024 + (long)chunk * SCAN_CL;

  for (int e = tid; e < SCAN_CL * 64; e += 256) {
    int l = e >> 6, col = e & 63;
    BC[l][col] = proj[(r0 + l) * 80 + 16 + col];
  }

  float A[16];
  {
    const float4* ap = (const float4*)(Aneg + ((long)(lidx * 256 + di)) * 32 + nh * 16);
#pragma unroll
    for (int q = 0; q < 4; ++q) {
      float4 v = ap[q];
      A[4 * q] = v.x; A[4 * q + 1] = v.y; A[4 * q + 2] = v.z; A[4 * q + 3] = v.w;
    }
  }

  const long sbase = (((long)jb * SCAN_NC + chunk) * 256 + di) * 32 + nh * 16;
  float h[16];
  if (PASS == 0) {
#pragma unroll
    for (int n = 0; n < 16; ++n) h[n] = 0.f;
  } else {
    const float4* hp = (const float4*)(HST + sbase);
#pragma unroll
    for (int q = 0; q < 4; ++q) {
      float4 v = hp[q];
      h[4 * q] = v.x; h[4 * q + 1] = v.y; h[4 * q + 2] = v.z; h[4 * q + 3] = v.w;
    }
  }

  float Dsk = 0.f, dtsum = 0.f;
  if (PASS == 1) Dsk = Dskip[lidx * 256 + di];

  const float* dtp = dt + r0 * 256 + di;
  const float* up  = uc + r0 * 256 + di;
  const float* zp0 = PG1 + (long)(j * 2) * G1PLANE + (r0 & 4095) * 512 + 256 + di;
  const float* zp1 = zp0 + G1PLANE;

  __syncthreads();

  float Db[2][8], Ub[2][8], Zb[2][8];
#pragma unroll
  for (int i = 0; i < 8; ++i) {
    Db[0][i] = dtp[(long)i * 256];
    Ub[0][i] = up[(long)i * 256];
    if (PASS == 1) Zb[0][i] = zp0[(long)i * 512] + zp1[(long)i * 512];
  }

#pragma unroll
  for (int bt = 0; bt < SCAN_CL / 8; ++bt) {
    const int cur = bt & 1, nxt = cur ^ 1;
    if (bt < SCAN_CL / 8 - 1) {
#pragma unroll
      for (int i = 0; i < 8; ++i) {
        long l = (long)(bt + 1) * 8 + i;
        Db[nxt][i] = dtp[l * 256];
        Ub[nxt][i] = up[l * 256];
        if (PASS == 1) Zb[nxt][i] = zp0[l * 512] + zp1[l * 512];
      }
    }
#pragma unroll
    for (int i = 0; i < 8; ++i) {
      const int l = bt * 8 + i;
      float dtv = Db[cur][i];
      float uv  = Ub[cur][i];
      float du  = dtv * uv;
      if (PASS == 0) dtsum += dtv;
      float yacc[4] = {0.f, 0.f, 0.f, 0.f};
      const float4* bc4 = (const float4*)&BC[l][nh * 16];
      const float4* cc4 = (const float4*)&BC[l][32 + nh * 16];
#pragma unroll
      for (int q = 0; q < 4; ++q) {
        float4 bv = bc4[q];
        float4 cv = cc4[q];
        const float* bp = &bv.x;
        const float* cp = &cv.x;
#pragma unroll
        for (int k = 0; k < 4; ++k) {
          int n = 4 * q + k;
          float a = EXP2(dtv * A[n]);     // A pre-scaled by log2(e)
          h[n] = fmaf(a, h[n], du * bp[k]);
          yacc[k] = fmaf(h[n], cp[k], yacc[k]);
        }
      }
      if (PASS == 1) {
        float p = (yacc[0] + yacc[1]) + (yacc[2] + yacc[3]);
        p += __shfl_xor(p, 1);            // add the other half's sum
        if (nh == 0) {
          float zv = Zb[cur][i];
          float val = (p + uv * Dsk) * siluf_(zv);
          long o = swzi((r0 + l) * 256 + di, r0 + l);
          split3_(val, YGh[o], YGm[o], YGl[o]);
        }
      }
    }
  }

  if (PASS == 0) {
    float4* hp = (float4*)(HST + sbase);
#pragma unroll
    for (int q = 0; q < 4; ++q)
      hp[q] = make_float4(h[4 * q], h[4 * q + 1], h[4 * q + 2], h[4 * q + 3]);
    if (nh == 0)
      DTS[((long)jb * SCAN_NC + chunk) * 256 + di] = dtsum;
  }
}

// ---------------- scan pass 2: sequential chunk combine (batched) ----------
__global__ __launch_bounds__(256)
void scan_combine_kernel(float* __restrict__ HST, const float* __restrict__ DTS,
                         const float* __restrict__ Aneg, int stage) {
  int t = blockIdx.x * 256 + threadIdx.x;   // 65536
  int n = t & 31;
  int di = (t >> 5) & 255;
  int jb = t >> 13;
  int lidx = stage + 2 * (jb >> 2);
  float A = Aneg[((long)(lidx * 256 + di)) * 32 + n];   // pre-scaled by log2e
  float hs = 0.f;
  for (int cb = 0; cb < SCAN_NC; cb += 8) {
    float s[8], P[8], hv[8];
#pragma unroll
    for (int i = 0; i < 8; ++i) {
      long base = ((long)jb * SCAN_NC + cb + i) * 256 + di;
      s[i] = HST[base * 32 + n];
      P[i] = DTS[base];
    }
#pragma unroll
    for (int i = 0; i < 8; ++i) P[i] = EXP2(A * P[i]);
#pragma unroll
    for (int i = 0; i < 8; ++i) {
      hv[i] = hs;
      hs = fmaf(P[i], hs, s[i]);
    }
#pragma unroll
    for (int i = 0; i < 8; ++i) {
      long base = ((long)jb * SCAN_NC + cb + i) * 256 + di;
      HST[base * 32 + n] = hv[i];
    }
  }
}

// ---------------- final combine (gate + s1 GEMM4 partials inline) ----------
__global__ __launch_bounds__(256) void combine_kernel(const float* __restrict__ PG,
                                                      long pz,
                                                      const float* __restrict__ PGATE,
                                                      const float* __restrict__ bg,
                                                      const float* __restrict__ alpha,
                                                      const float* __restrict__ gamma,
                                                      const float* __restrict__ beta,
                                                      float* __restrict__ out) {
  const long GZ = 1024L * 1024;
  long idx = (long)blockIdx.x * 256 + threadIdx.x;  // 1,048,576 (b,d,l)
  int l = (int)(idx & 1023);
  long t = idx >> 10;
  int d = (int)(t & 255);
  int b = (int)(t >> 8);
  int lr = 1023 - l;
  long b0 = ((long)(b * 1024 + l)) * 256 + d;        // z=0 plane row
  long b1 = ((long)(b * 1024 + lr)) * 256 + d;       // z=1 plane row
  float h0 = PG[b0] + PG[pz + b0];
  float h1 = PG[2 * pz + b1] + PG[3 * pz + b1];
  long gi0 = ((long)(b * 256 + d)) * 1024 + l;
  long gi1 = ((long)(b * 256 + d)) * 1024 + lr;
  float g0 = sigmoidf_((PGATE[gi0] + PGATE[GZ + gi0]) + bg[l]);
  float g1 = sigmoidf_((PGATE[2 * GZ + gi1] + PGATE[3 * GZ + gi1]) + bg[1024 + lr]);
  float m0 = (gamma[l] * tanhf(alpha[0] * h0) + beta[l]) * g0;
  float m1 = (gamma[1024 + lr] * tanhf(alpha[1] * h1) + beta[1024 + lr]) * g1;
  out[idx] = m0 + m1;
}

// ---------------------------------------------------------------------------
extern "C" void kernel_launch(void* const* d_in, const int* in_sizes, int n_in,
                              void* d_out, int out_size, void* d_ws, size_t ws_size,
                              hipStream_t stream) {
  const float* x     = (const float*)d_in[0];
  const float* Win   = (const float*)d_in[1];
  const float* Wconv = (const float*)d_in[2];
  const float* bconv = (const float*)d_in[3];
  const float* Wxp   = (const float*)d_in[4];
  const float* Wdt   = (const float*)d_in[5];
  const float* bdt   = (const float*)d_in[6];
  const float* Alog  = (const float*)d_in[7];
  const float* Dskip = (const float*)d_in[8];
  const float* Wout  = (const float*)d_in[9];
  const float* Wg    = (const float*)d_in[10];
  const float* bg    = (const float*)d_in[11];
  const float* alpha = (const float*)d_in[12];
  const float* gamma = (const float*)d_in[13];
  const float* beta  = (const float*)d_in[14];
  float* out = (float*)d_out;

  // ---- workspace layout (ws = 256 MB; used ~150 MB). PG = GEMM4 partials
  // (s0 consumed by combine2<2>, s1 by the final combine). PGATE = gate
  // partials (consumed only by the final combine). PG1 = GEMM1 partials
  // (consumed by gemm23 + scan, overwritten next stage). ----
  float* ws    = (float*)d_ws;
  float* PG1   = ws;                    // 8,388,608 f (2 planes x 4096x512)
  float* UC    = PG1 + 8388608;         // 2,097,152 f
  float* PROJ  = UC + 2097152;          // 655,360 f
  float* DT    = PROJ + 655360;         // 2,097,152 f
  float* PGATE = DT + 2097152;          // 4,194,304 f (4 planes x 1M)
  float* ANEG  = PGATE + 4194304;       // 32,768 f
  float* HST   = ANEG + 32768;          // 4,194,304 f  (NC=64)
  float* DTS   = HST + 4194304;         // 131,072 f
  float* PG    = DTS + 131072;          // 4,194,304 f (GEMM4 partials)
  unsigned short* Xpl  = (unsigned short*)(PG + 4194304);   // 3 x 2,097,152 u16
  unsigned short* YGpl = Xpl + 3 * 2097152;                 // 3 x 2,097,152 u16
  unsigned short* XGpl = YGpl + 3 * 2097152;                // 3 x 1,048,576 u16
  unsigned short* Wgpl = XGpl + 3 * 1048576;                // 3 x 2,097,152 u16
  unsigned short* WinT = Wgpl + 3 * 2097152;                // 3 x 524,288 u16
  unsigned short* WoutT = WinT + 3 * 524288;                // 3 x 262,144 u16
  unsigned short* Xh = Xpl, *Xm = Xpl + 2097152, *Xl = Xpl + 2 * 2097152;
  unsigned short* YGh = YGpl, *YGm = YGpl + 2097152, *YGl = YGpl + 2 * 2097152;
  unsigned short* XGh = XGpl, *XGm = XGpl + 1048576, *XGl = XGpl + 2 * 1048576;
  unsigned short* Wgh = Wgpl, *Wgm = Wgpl + 2097152, *Wgl = Wgpl + 2 * 2097152;
  unsigned short* WinTh = WinT, *WinTm = WinT + 524288, *WinTl = WinT + 2 * 524288;
  unsigned short* WoutTh = WoutT, *WoutTm = WoutT + 262144, *WoutTl = WoutT + 2 * 262144;

  // ---- fused preprocessing (1 dispatch) ----
  preprocess_kernel<<<dim3(12160), dim3(256), 0, stream>>>(
      x, Wg, Win, Wout, Alog, Xh, Xm, Xl, XGh, XGm, XGl,
      Wgh, Wgm, Wgl, WinTh, WinTm, WinTl, WoutTh, WoutTm, WoutTl, ANEG);

  // ---- gate: K-split x2 (256 blocks) -> PGATE (no combine dispatch; the
  // final combine computes sigmoid(p0+p1+bg) inline) ----
  gemm_mfma<2><<<dim3(8, 8, 4), dim3(256), 0, stream>>>(
      XGh, XGm, XGl, 0L, 1024,
      Wgh, Wgm, Wgl, (long)1024 * 1024, 1024,
      PGATE, (long)1024 * 1024, 1024, 512);

  for (int s = 0; s < 2; ++s) {
    // GEMM1: K-split x2 (512 blocks = 2/CU), partials in PG1; consumers sum
    gemm_mfma<2><<<dim3(4, 32, 4), dim3(256), 0, stream>>>(
        Xh, Xm, Xl, (long)4096 * 256, 256,
        WinTh + (long)s * 131072, WinTm + (long)s * 131072, WinTl + (long)s * 131072,
        (long)262144, 256,
        PG1, G1PLANE, 512, 128);

    // fused CONV + GEMM2 + GEMM3 (512 blocks; sums GEMM1 partials)
    gemm23_kernel<<<dim3(256, 2), dim3(256), 0, stream>>>(
        PG1, Wconv, bconv, Wxp, Wdt, bdt, UC, PROJ, DT, s);

    // chunked selective scan (3 dispatches; 1024-block chunk kernels)
    scan_chunk_kernel<0><<<dim3(2 * 8 * SCAN_NC), dim3(256), 0, stream>>>(
        DT, UC, PG1, PROJ, ANEG, Dskip, HST, DTS, YGh, YGm, YGl, s);
    scan_combine_kernel<<<dim3(256), dim3(256), 0, stream>>>(HST, DTS, ANEG, s);
    scan_chunk_kernel<1><<<dim3(2 * 8 * SCAN_NC), dim3(256), 0, stream>>>(
        DT, UC, PG1, PROJ, ANEG, Dskip, HST, DTS, YGh, YGm, YGl, s);

    // GEMM4: K-split x2 (256 blocks)
    gemm_mfma<2><<<dim3(2, 32, 4), dim3(256), 0, stream>>>(
        YGh, YGm, YGl, (long)4096 * 256, 256,
        WoutTh + (long)s * 65536, WoutTm + (long)s * 65536, WoutTl + (long)s * 65536,
        (long)131072, 256,
        PG, (long)4096 * 256, 256, 128);
    if (s == 0) {
      combine2_kernel<2><<<dim3(4096, 2), dim3(256), 0, stream>>>(
          PG, (long)4096 * 256, nullptr, Xh, Xm, Xl, (long)4096 * 256);
    }
    // s1: no combine -- final combine sums the partial planes inline
  }

  combine_kernel<<<dim3(4096), dim3(256), 0, stream>>>(
      PG, (long)4096 * 256, PGATE, bg, alpha, gamma, beta, out);
}

// Round 23
// 280.540 us; speedup vs baseline: 1.0480x; 1.0480x over previous
//
#include <hip/hip_runtime.h>

// ---------------------------------------------------------------------------
// MambaLatentBiMap: 2 branches (fwd / reversed) x 2 mamba layers + gates.
// Rows r = (j, b, l). Layer index for stage s, branch j: lidx = s + 2*j.
// MFMA GEMMs: EXACT 3-way bf16 split (6 product terms -> fp32-equivalent),
// operands pre-split into 3 u16 planes; global_load_lds staging; PRE-SWIZZLED
// global plane layout (swzi) for conflict-free ds_read_b128.
// Round-23: r21 best (286.9us) + ONLY the gate-inline half of r22's bundle
// (r22's GEMM1 K-split pushed +16MB of partial-plane reads into gemm23/scan
// and regressed): gate partials -> PGATE, combine2<1> dispatch dropped, the
// final combine computes sigmoid((p0+p1)+bg) inline (same summation order ->
// bit-identical). GEMM1 back to full-K -> UZ.
// Config: 2-deep pipelined gemm_mfma (counted vmcnt(12)), conv fused into
// gemm23, gate/GEMM4 K-split x2, scan state-split thread pairs (16 states/
// thread, 1024 blocks), s1 GEMM4 combine folded into final combine.
// ---------------------------------------------------------------------------

#define LSEQ 1024
#define SCAN_CL 16
#define SCAN_NC 64

#if __has_builtin(__builtin_amdgcn_exp2f)
#define EXP2(x) __builtin_amdgcn_exp2f(x)
#else
#define EXP2(x) exp2f(x)
#endif

typedef short bf16x8 __attribute__((ext_vector_type(8)));
typedef float f32x4 __attribute__((ext_vector_type(4)));

__device__ __forceinline__ float sigmoidf_(float x) { return 1.f / (1.f + __expf(-x)); }
__device__ __forceinline__ float siluf_(float x)    { return x / (1.f + __expf(-x)); }
__device__ __forceinline__ float softplusf_(float x){ return x > 20.f ? x : log1pf(__expf(x)); }

__device__ __forceinline__ unsigned short bf16rne_(float v) {
  unsigned u = __float_as_uint(v);
  return (unsigned short)((u + 0x7FFFu + ((u >> 16) & 1u)) >> 16);
}
__device__ __forceinline__ float bfto_(unsigned short h) {
  return __uint_as_float(((unsigned)h) << 16);
}
__device__ __forceinline__ void split3_(float v, unsigned short& h,
                                        unsigned short& m, unsigned short& l) {
  h = bf16rne_(v); float r = v - bfto_(h);
  m = bf16rne_(r); float r2 = r - bfto_(m);
  l = bf16rne_(r2);
}

// swizzle: XOR k-bits 3-4 of a u16 plane index with row bits 1-2 (involution;
// valid since every plane K-dim is a multiple of 32).
__device__ __forceinline__ long swzi(long idx, long row) {
  return idx ^ (((row >> 1) & 3) << 3);
}

// ---------------- fused preprocessing (1 dispatch) -------------------------
__device__ void tconv3_body(const float* __restrict__ in,
                            unsigned short* __restrict__ oh,
                            unsigned short* __restrict__ om,
                            unsigned short* __restrict__ ol,
                            int K, int N, int bx, int by, int z) {
  __shared__ float T[32][33];
  int n0 = bx * 32, k0 = by * 32;
  int tx = threadIdx.x & 31, ty = threadIdx.x >> 5;   // 32 x 8
  const float* src = in + (long)z * K * N;
#pragma unroll
  for (int m = 0; m < 4; ++m)
    T[ty + 8 * m][tx] = src[(long)(k0 + ty + 8 * m) * N + n0 + tx];
  __syncthreads();
  long obase = (long)z * N * K;
#pragma unroll
  for (int m = 0; m < 4; ++m) {
    float v = T[tx][ty + 8 * m];
    int n = n0 + ty + 8 * m;
    long o = swzi(obase + (long)n * K + k0 + tx, n);
    split3_(v, oh[o], om[o], ol[o]);
  }
}

__device__ void split3v_body(const float4* __restrict__ in,
                             unsigned short* __restrict__ oh,
                             unsigned short* __restrict__ om,
                             unsigned short* __restrict__ ol, int i) {
  float4 v = in[i];
  long b = 4L * i;                     // u16 base index; row = b >> 10 (K=1024)
  long sb = swzi(b, b >> 10);
  ushort4 H, M, L;
  split3_(v.x, H.x, M.x, L.x); split3_(v.y, H.y, M.y, L.y);
  split3_(v.z, H.z, M.z, L.z); split3_(v.w, H.w, M.w, L.w);
  *(ushort4*)(oh + sb) = H; *(ushort4*)(om + sb) = M; *(ushort4*)(ol + sb) = L;
}

__global__ __launch_bounds__(256)
void preprocess_kernel(const float* __restrict__ x, const float* __restrict__ Wg,
                       const float* __restrict__ Win, const float* __restrict__ Wout,
                       const float* __restrict__ Alog,
                       unsigned short* __restrict__ Xh, unsigned short* __restrict__ Xm,
                       unsigned short* __restrict__ Xl,
                       unsigned short* __restrict__ XGh, unsigned short* __restrict__ XGm,
                       unsigned short* __restrict__ XGl,
                       unsigned short* __restrict__ Wgh, unsigned short* __restrict__ Wgm,
                       unsigned short* __restrict__ Wgl,
                       unsigned short* __restrict__ WinTh, unsigned short* __restrict__ WinTm,
                       unsigned short* __restrict__ WinTl,
                       unsigned short* __restrict__ WoutTh, unsigned short* __restrict__ WoutTm,
                       unsigned short* __restrict__ WoutTl,
                       float* __restrict__ Aneg) {
  const int bid = blockIdx.x;
  if (bid < 8192) {                       // prep: x (B,D,L) -> X planes
    long idx = (long)bid * 256 + threadIdx.x;
    int d = (int)(idx & 255);
    long t = idx >> 8;
    int l = (int)(t & 1023);
    int t2 = (int)(t >> 10);
    int b = t2 & 3;
    int j = t2 >> 2;
    int lsrc = j ? (1023 - l) : l;
    float v = x[((long)(b * 256 + d)) * LSEQ + lsrc];
    long o = swzi(idx, t);
    split3_(v, Xh[o], Xm[o], Xl[o]);
  } else if (bid < 9216) {                // split x -> XG planes (K=1024)
    int i = (bid - 8192) * 256 + threadIdx.x;
    split3v_body((const float4*)x, XGh, XGm, XGl, i);
  } else if (bid < 11264) {               // split Wg -> planes (K=1024)
    int i = (bid - 9216) * 256 + threadIdx.x;
    split3v_body((const float4*)Wg, Wgh, Wgm, Wgl, i);
  } else if (bid < 11776) {               // tconv3 Win (K=256,N=512, z=4)
    int t = bid - 11264;                  // dim3(16,8,4)
    tconv3_body(Win, WinTh, WinTm, WinTl, 256, 512, t & 15, (t >> 4) & 7, t >> 7);
  } else if (bid < 12032) {               // tconv3 Wout (K=256,N=256, z=4)
    int t = bid - 11776;                  // dim3(8,8,4)
    tconv3_body(Wout, WoutTh, WoutTm, WoutTl, 256, 256, t & 7, (t >> 3) & 7, t >> 6);
  } else {                                // aneg: -exp(Alog)*log2(e)
    int idx = (bid - 12032) * 256 + threadIdx.x;   // 32768
    Aneg[idx] = -__expf(Alog[idx]) * 1.4426950408889634f;
  }
}

// ---------------- MFMA 3-split bf16 GEMM (2-deep pipelined staging) --------
__device__ __forceinline__ void gload16(const unsigned short* g, unsigned short* l) {
  __builtin_amdgcn_global_load_lds(
      (const __attribute__((address_space(1))) unsigned int*)g,
      (__attribute__((address_space(3))) unsigned int*)l, 16, 0, 0);
}

template <int KSPLIT>
__global__ __launch_bounds__(256)
void gemm_mfma(const unsigned short* __restrict__ Ah_g,
               const unsigned short* __restrict__ Am_g,
               const unsigned short* __restrict__ Al_g, long aZ, int lda,
               const unsigned short* __restrict__ Bh_g,
               const unsigned short* __restrict__ Bm_g,
               const unsigned short* __restrict__ Bl_g, long bZ, int ldb,
               float* __restrict__ C, long cZ, int N, int KH) {
  __shared__ unsigned short S[2][6][128 * 32];   // double-buffered, 96 KB
  const int bz = blockIdx.z;
  const int z  = (KSPLIT == 2) ? (bz >> 1) : bz;
  const int kh = (KSPLIT == 2) ? (bz & 1) : 0;
  const int m0 = blockIdx.y * 128, n0 = blockIdx.x * 128;
  const int tid = threadIdx.x;

  const long khoff = (long)kh * KH;
  const long a0 = (long)z * aZ + (long)(m0 + (tid >> 2)) * lda + khoff + (tid & 3) * 8;
  const long a1 = a0 + 64L * lda;
  const long b0 = (long)z * bZ + (long)(n0 + (tid >> 2)) * ldb + khoff + (tid & 3) * 8;
  const long b1 = b0 + 64L * ldb;
  const int l0 = tid * 8, l1 = tid * 8 + 2048;   // u16 offsets into S[b][p]

  const int lane = tid & 63, w = tid >> 6;
  const int wr = w >> 1, wc = w & 1;
  const int fr = lane & 15, g = lane >> 4;

  f32x4 acc[4][4];
#pragma unroll
  for (int i = 0; i < 4; ++i)
#pragma unroll
    for (int j = 0; j < 4; ++j)
#pragma unroll
      for (int q = 0; q < 4; ++q) acc[i][j][q] = 0.f;

#define ISSUE_TILE(B, KOFF)                                 \
  do {                                                      \
    gload16(Ah_g + a0 + (KOFF), &S[B][0][l0]);              \
    gload16(Ah_g + a1 + (KOFF), &S[B][0][l1]);              \
    gload16(Am_g + a0 + (KOFF), &S[B][1][l0]);              \
    gload16(Am_g + a1 + (KOFF), &S[B][1][l1]);              \
    gload16(Al_g + a0 + (KOFF), &S[B][2][l0]);              \
    gload16(Al_g + a1 + (KOFF), &S[B][2][l1]);              \
    gload16(Bh_g + b0 + (KOFF), &S[B][3][l0]);              \
    gload16(Bh_g + b1 + (KOFF), &S[B][3][l1]);              \
    gload16(Bm_g + b0 + (KOFF), &S[B][4][l0]);              \
    gload16(Bm_g + b1 + (KOFF), &S[B][4][l1]);              \
    gload16(Bl_g + b0 + (KOFF), &S[B][5][l0]);              \
    gload16(Bl_g + b1 + (KOFF), &S[B][5][l1]);              \
  } while (0)

  ISSUE_TILE(0, 0);                      // prologue: tile 0 in flight
  int cur = 0;

  for (int k0 = 0; k0 < KH; k0 += 32) {
    asm volatile("s_waitcnt lgkmcnt(0)" ::: "memory");
    __builtin_amdgcn_s_barrier();
    if (k0 + 32 < KH) {
      ISSUE_TILE(cur ^ 1, k0 + 32);      // next tile into the free buffer
      asm volatile("s_waitcnt vmcnt(12)" ::: "memory");  // cur's 12 done
    } else {
      asm volatile("s_waitcnt vmcnt(0)" ::: "memory");   // drain last tile
    }
    __builtin_amdgcn_s_barrier();        // cur buffer visible everywhere
    __builtin_amdgcn_sched_barrier(0);

    bf16x8 fb[3][4];
#pragma unroll
    for (int nf = 0; nf < 4; ++nf) {
      int rb = wc * 64 + nf * 16 + fr;
      int ob = rb * 32 + ((g ^ ((rb >> 1) & 3)) << 3);
      fb[0][nf] = *(const bf16x8*)&S[cur][3][ob];
      fb[1][nf] = *(const bf16x8*)&S[cur][4][ob];
      fb[2][nf] = *(const bf16x8*)&S[cur][5][ob];
    }
#pragma unroll
    for (int mf = 0; mf < 4; ++mf) {
      int ra = wr * 64 + mf * 16 + fr;
      int oa = ra * 32 + ((g ^ ((ra >> 1) & 3)) << 3);
      bf16x8 fah = *(const bf16x8*)&S[cur][0][oa];
      bf16x8 fam = *(const bf16x8*)&S[cur][1][oa];
      bf16x8 fal = *(const bf16x8*)&S[cur][2][oa];
#pragma unroll
      for (int nf = 0; nf < 4; ++nf) {
        acc[mf][nf] = __builtin_amdgcn_mfma_f32_16x16x32_bf16(fah, fb[0][nf], acc[mf][nf], 0, 0, 0);
        acc[mf][nf] = __builtin_amdgcn_mfma_f32_16x16x32_bf16(fah, fb[1][nf], acc[mf][nf], 0, 0, 0);
        acc[mf][nf] = __builtin_amdgcn_mfma_f32_16x16x32_bf16(fam, fb[0][nf], acc[mf][nf], 0, 0, 0);
        acc[mf][nf] = __builtin_amdgcn_mfma_f32_16x16x32_bf16(fam, fb[1][nf], acc[mf][nf], 0, 0, 0);
        acc[mf][nf] = __builtin_amdgcn_mfma_f32_16x16x32_bf16(fah, fb[2][nf], acc[mf][nf], 0, 0, 0);
        acc[mf][nf] = __builtin_amdgcn_mfma_f32_16x16x32_bf16(fal, fb[0][nf], acc[mf][nf], 0, 0, 0);
      }
    }
    cur ^= 1;
  }
#undef ISSUE_TILE

  float* Cz = C + (long)bz * cZ;
#pragma unroll
  for (int mf = 0; mf < 4; ++mf)
#pragma unroll
    for (int nf = 0; nf < 4; ++nf) {
      int col = n0 + wc * 64 + nf * 16 + fr;
      int row0 = m0 + wr * 64 + mf * 16 + g * 4;
#pragma unroll
      for (int q = 0; q < 4; ++q)
        Cz[(long)(row0 + q) * N + col] = acc[mf][nf][q];
    }
}

// ---------------- combine2: sum two K-split partial planes -> split planes -
__global__ __launch_bounds__(256)
void combine2_kernel(const float* __restrict__ P, long pz,
                     unsigned short* __restrict__ oh,
                     unsigned short* __restrict__ om,
                     unsigned short* __restrict__ ol, long oz) {
  int z = blockIdx.y;
  long i = (long)blockIdx.x * 256 + threadIdx.x;
  float v = P[(long)(2 * z) * pz + i] + P[(long)(2 * z + 1) * pz + i];
  long o = (long)z * oz + swzi(i, i >> 8);   // row = i>>8, K = 256
  split3_(v, oh[o], om[o], ol[o]);
}

// ---------------- fused CONV + GEMM2 + GEMM3 (BM=16, 512 blocks) -----------
__global__ __launch_bounds__(256)
void gemm23_kernel(const float* __restrict__ UZ, const float* __restrict__ Wconv,
                   const float* __restrict__ bconv,
                   const float* __restrict__ Wxp,
                   const float* __restrict__ Wdt, const float* __restrict__ bdt,
                   float* __restrict__ UC, float* __restrict__ PROJ,
                   float* __restrict__ DTo, int stage) {
  __shared__ float UZt[19][256];   // u rows m0-3..m0+15
  __shared__ float ucs[16][260];   // conv output (padded: bank-spread)
  __shared__ float Ws[16][80];
  __shared__ float PR[16][17];
  __shared__ float WD[16][256];
  const int z = blockIdx.y;
  const int lidx = stage + 2 * z;
  const int m0 = blockIdx.x * 16;                    // within 4096
  const int l0 = m0 & 1023;
  const float* W = Wxp + (long)lidx * 256 * 80;
  const int tid = threadIdx.x;
  const int tx = tid & 15, ty = tid >> 4;

#pragma unroll
  for (int t = 0; t < 16; ++t) {
    int e = t * 256 + tid;
    WD[e >> 8][e & 255] = Wdt[(long)lidx * 4096 + e];
  }

  {
    const long base = ((long)z * 4096 + m0 - 3) * 512 + tid;
#pragma unroll
    for (int r = 0; r < 19; ++r)
      UZt[r][tid] = (l0 == 0 && r < 3) ? 0.f : UZ[base + (long)r * 512];
  }
  __syncthreads();

  {
    const float* wcp = Wconv + (long)(lidx * 256 + tid) * 4;
    float w0 = wcp[0], w1 = wcp[1], w2 = wcp[2], w3 = wcp[3];
    float bcv = bconv[lidx * 256 + tid];
#pragma unroll
    for (int it = 0; it < 16; ++it) {
      float acc = bcv;
      acc = fmaf(UZt[it + 0][tid], w0, acc);
      acc = fmaf(UZt[it + 1][tid], w1, acc);
      acc = fmaf(UZt[it + 2][tid], w2, acc);
      acc = fmaf(UZt[it + 3][tid], w3, acc);
      float ucv = acc * sigmoidf_(acc);
      UC[((long)z * 4096 + m0 + it) * 256 + tid] = ucv;
      ucs[it][tid] = ucv;
    }
  }
  __syncthreads();

  float acc[5];
#pragma unroll
  for (int j = 0; j < 5; ++j) acc[j] = 0.f;

  for (int k0 = 0; k0 < 256; k0 += 16) {
    {
      int k = tid >> 4, cg2 = (tid & 15) * 5;
#pragma unroll
      for (int i2 = 0; i2 < 5; ++i2)
        Ws[k][cg2 + i2] = W[(long)(k0 + k) * 80 + cg2 + i2];
    }
    __syncthreads();
#pragma unroll
    for (int kk = 0; kk < 16; ++kk) {
      float a = ucs[ty][k0 + kk];
#pragma unroll
      for (int j = 0; j < 5; ++j)
        acc[j] = fmaf(a, Ws[kk][tx * 5 + j], acc[j]);
    }
    __syncthreads();
  }

#pragma unroll
  for (int j = 0; j < 5; ++j) {
    int c = tx * 5 + j;
    float v = acc[j];
    PROJ[((long)z * 4096 + m0 + ty) * 80 + c] = v;
    if (c < 16) PR[ty][c] = v;
  }
  __syncthreads();

  for (int it = 0; it < 16; ++it) {
    float ssum = 0.f;
#pragma unroll
    for (int k = 0; k < 16; ++k) ssum = fmaf(PR[it][k], WD[k][tid], ssum);
    DTo[((long)z * 4096 + m0 + it) * 256 + tid] =
        softplusf_(ssum + bdt[lidx * 256 + tid]);
  }
}

// ---------------- selective scan: chunked, state-split thread pairs --------
template <int PASS>
__global__ __launch_bounds__(256)
void scan_chunk_kernel(const float* __restrict__ dt,
                       const float* __restrict__ uc,
                       const float* __restrict__ UZ,
                       const float* __restrict__ proj,
                       const float* __restrict__ Aneg,
                       const float* __restrict__ Dskip,
                       float* __restrict__ HST,   // [8][NC][256][32]
                       float* __restrict__ DTS,   // [8][NC][256]
                       unsigned short* __restrict__ YGh,
                       unsigned short* __restrict__ YGm,
                       unsigned short* __restrict__ YGl, int stage) {
  __shared__ __align__(16) float BC[SCAN_CL][64];
  const int blk = blockIdx.x;
  const int c128 = blk & 1;
  const int chunk = (blk >> 1) & (SCAN_NC - 1);
  const int jb = blk >> 7;
  const int tid = threadIdx.x;
  const int di = c128 * 128 + (tid >> 1);
  const int nh = tid & 1;
  const int j = jb >> 2;
  const int lidx = stage + 2 * j;
  const long r0 = (long)jb * 1024 + (long)chunk * SCAN_CL;

  for (int e = tid; e < SCAN_CL * 64; e += 256) {
    int l = e >> 6, col = e & 63;
    BC[l][col] = proj[(r0 + l) * 80 + 16 + col];
  }

  float A[16];
  {
    const float4* ap = (const float4*)(Aneg + ((long)(lidx * 256 + di)) * 32 + nh * 16);
#pragma unroll
    for (int q = 0; q < 4; ++q) {
      float4 v = ap[q];
      A[4 * q] = v.x; A[4 * q + 1] = v.y; A[4 * q + 2] = v.z; A[4 * q + 3] = v.w;
    }
  }

  const long sbase = (((long)jb * SCAN_NC + chunk) * 256 + di) * 32 + nh * 16;
  float h[16];
  if (PASS == 0) {
#pragma unroll
    for (int n = 0; n < 16; ++n) h[n] = 0.f;
  } else {
    const float4* hp = (const float4*)(HST + sbase);
#pragma unroll
    for (int q = 0; q < 4; ++q) {
      float4 v = hp[q];
      h[4 * q] = v.x; h[4 * q + 1] = v.y; h[4 * q + 2] = v.z; h[4 * q + 3] = v.w;
    }
  }

  float Dsk = 0.f, dtsum = 0.f;
  if (PASS == 1) Dsk = Dskip[lidx * 256 + di];

  const float* dtp = dt + r0 * 256 + di;
  const float* up  = uc + r0 * 256 + di;
  const float* zp  = UZ + r0 * 512 + 256 + di;

  __syncthreads();

  float Db[2][8], Ub[2][8], Zb[2][8];
#pragma unroll
  for (int i = 0; i < 8; ++i) {
    Db[0][i] = dtp[(long)i * 256];
    Ub[0][i] = up[(long)i * 256];
    if (PASS == 1) Zb[0][i] = zp[(long)i * 512];
  }

#pragma unroll
  for (int bt = 0; bt < SCAN_CL / 8; ++bt) {
    const int cur = bt & 1, nxt = cur ^ 1;
    if (bt < SCAN_CL / 8 - 1) {
#pragma unroll
      for (int i = 0; i < 8; ++i) {
        long l = (long)(bt + 1) * 8 + i;
        Db[nxt][i] = dtp[l * 256];
        Ub[nxt][i] = up[l * 256];
        if (PASS == 1) Zb[nxt][i] = zp[l * 512];
      }
    }
#pragma unroll
    for (int i = 0; i < 8; ++i) {
      const int l = bt * 8 + i;
      float dtv = Db[cur][i];
      float uv  = Ub[cur][i];
      float du  = dtv * uv;
      if (PASS == 0) dtsum += dtv;
      float yacc[4] = {0.f, 0.f, 0.f, 0.f};
      const float4* bc4 = (const float4*)&BC[l][nh * 16];
      const float4* cc4 = (const float4*)&BC[l][32 + nh * 16];
#pragma unroll
      for (int q = 0; q < 4; ++q) {
        float4 bv = bc4[q];
        float4 cv = cc4[q];
        const float* bp = &bv.x;
        const float* cp = &cv.x;
#pragma unroll
        for (int k = 0; k < 4; ++k) {
          int n = 4 * q + k;
          float a = EXP2(dtv * A[n]);     // A pre-scaled by log2(e)
          h[n] = fmaf(a, h[n], du * bp[k]);
          yacc[k] = fmaf(h[n], cp[k], yacc[k]);
        }
      }
      if (PASS == 1) {
        float p = (yacc[0] + yacc[1]) + (yacc[2] + yacc[3]);
        p += __shfl_xor(p, 1);            // add the other half's sum
        if (nh == 0) {
          float zv = Zb[cur][i];
          float val = (p + uv * Dsk) * siluf_(zv);
          long o = swzi((r0 + l) * 256 + di, r0 + l);
          split3_(val, YGh[o], YGm[o], YGl[o]);
        }
      }
    }
  }

  if (PASS == 0) {
    float4* hp = (float4*)(HST + sbase);
#pragma unroll
    for (int q = 0; q < 4; ++q)
      hp[q] = make_float4(h[4 * q], h[4 * q + 1], h[4 * q + 2], h[4 * q + 3]);
    if (nh == 0)
      DTS[((long)jb * SCAN_NC + chunk) * 256 + di] = dtsum;
  }
}

// ---------------- scan pass 2: sequential chunk combine (batched) ----------
__global__ __launch_bounds__(256)
void scan_combine_kernel(float* __restrict__ HST, const float* __restrict__ DTS,
                         const float* __restrict__ Aneg, int stage) {
  int t = blockIdx.x * 256 + threadIdx.x;   // 65536
  int n = t & 31;
  int di = (t >> 5) & 255;
  int jb = t >> 13;
  int lidx = stage + 2 * (jb >> 2);
  float A = Aneg[((long)(lidx * 256 + di)) * 32 + n];   // pre-scaled by log2e
  float hs = 0.f;
  for (int cb = 0; cb < SCAN_NC; cb += 8) {
    float s[8], P[8], hv[8];
#pragma unroll
    for (int i = 0; i < 8; ++i) {
      long base = ((long)jb * SCAN_NC + cb + i) * 256 + di;
      s[i] = HST[base * 32 + n];
      P[i] = DTS[base];
    }
#pragma unroll
    for (int i = 0; i < 8; ++i) P[i] = EXP2(A * P[i]);
#pragma unroll
    for (int i = 0; i < 8; ++i) {
      hv[i] = hs;
      hs = fmaf(P[i], hs, s[i]);
    }
#pragma unroll
    for (int i = 0; i < 8; ++i) {
      long base = ((long)jb * SCAN_NC + cb + i) * 256 + di;
      HST[base * 32 + n] = hv[i];
    }
  }
}

// ---------------- final combine (gate + s1 GEMM4 partials inline) ----------
__global__ __launch_bounds__(256) void combine_kernel(const float* __restrict__ PG,
                                                      long pz,
                                                      const float* __restrict__ PGATE,
                                                      const float* __restrict__ bg,
                                                      const float* __restrict__ alpha,
                                                      const float* __restrict__ gamma,
                                                      const float* __restrict__ beta,
                                                      float* __restrict__ out) {
  const long GZ = 1024L * 1024;
  long idx = (long)blockIdx.x * 256 + threadIdx.x;  // 1,048,576 (b,d,l)
  int l = (int)(idx & 1023);
  long t = idx >> 10;
  int d = (int)(t & 255);
  int b = (int)(t >> 8);
  int lr = 1023 - l;
  long b0 = ((long)(b * 1024 + l)) * 256 + d;        // z=0 plane row
  long b1 = ((long)(b * 1024 + lr)) * 256 + d;       // z=1 plane row
  float h0 = PG[b0] + PG[pz + b0];
  float h1 = PG[2 * pz + b1] + PG[3 * pz + b1];
  long gi0 = ((long)(b * 256 + d)) * 1024 + l;
  long gi1 = ((long)(b * 256 + d)) * 1024 + lr;
  float g0 = sigmoidf_((PGATE[gi0] + PGATE[GZ + gi0]) + bg[l]);
  float g1 = sigmoidf_((PGATE[2 * GZ + gi1] + PGATE[3 * GZ + gi1]) + bg[1024 + lr]);
  float m0 = (gamma[l] * tanhf(alpha[0] * h0) + beta[l]) * g0;
  float m1 = (gamma[1024 + lr] * tanhf(alpha[1] * h1) + beta[1024 + lr]) * g1;
  out[idx] = m0 + m1;
}

// ---------------------------------------------------------------------------
extern "C" void kernel_launch(void* const* d_in, const int* in_sizes, int n_in,
                              void* d_out, int out_size, void* d_ws, size_t ws_size,
                              hipStream_t stream) {
  const float* x     = (const float*)d_in[0];
  const float* Win   = (const float*)d_in[1];
  const float* Wconv = (const float*)d_in[2];
  const float* bconv = (const float*)d_in[3];
  const float* Wxp   = (const float*)d_in[4];
  const float* Wdt   = (const float*)d_in[5];
  const float* bdt   = (const float*)d_in[6];
  const float* Alog  = (const float*)d_in[7];
  const float* Dskip = (const float*)d_in[8];
  const float* Wout  = (const float*)d_in[9];
  const float* Wg    = (const float*)d_in[10];
  const float* bg    = (const float*)d_in[11];
  const float* alpha = (const float*)d_in[12];
  const float* gamma = (const float*)d_in[13];
  const float* beta  = (const float*)d_in[14];
  float* out = (float*)d_out;

  // ---- workspace layout (ws = 256 MB). PGATE = gate partials (consumed
  // only by the final combine). PG = GEMM4 partials (s0 consumed by
  // combine2, s1 by the final combine). ----
  float* ws    = (float*)d_ws;
  float* UZ    = ws;                    // 4,194,304 f
  float* UC    = UZ + 4194304;          // 2,097,152 f
  float* PROJ  = UC + 2097152;          // 655,360 f
  float* DT    = PROJ + 655360;         // 2,097,152 f
  float* PGATE = DT + 2097152;          // 4,194,304 f (4 planes x 1M)
  float* ANEG  = PGATE + 4194304;       // 32,768 f
  float* HST   = ANEG + 32768;          // 4,194,304 f  (NC=64)
  float* DTS   = HST + 4194304;         // 131,072 f
  float* PG    = DTS + 131072;          // 4,194,304 f (GEMM4 partials)
  unsigned short* Xpl  = (unsigned short*)(PG + 4194304);   // 3 x 2,097,152 u16
  unsigned short* YGpl = Xpl + 3 * 2097152;                 // 3 x 2,097,152 u16
  unsigned short* XGpl = YGpl + 3 * 2097152;                // 3 x 1,048,576 u16
  unsigned short* Wgpl = XGpl + 3 * 1048576;                // 3 x 2,097,152 u16
  unsigned short* WinT = Wgpl + 3 * 2097152;                // 3 x 524,288 u16
  unsigned short* WoutT = WinT + 3 * 524288;                // 3 x 262,144 u16
  unsigned short* Xh = Xpl, *Xm = Xpl + 2097152, *Xl = Xpl + 2 * 2097152;
  unsigned short* YGh = YGpl, *YGm = YGpl + 2097152, *YGl = YGpl + 2 * 2097152;
  unsigned short* XGh = XGpl, *XGm = XGpl + 1048576, *XGl = XGpl + 2 * 1048576;
  unsigned short* Wgh = Wgpl, *Wgm = Wgpl + 2097152, *Wgl = Wgpl + 2 * 2097152;
  unsigned short* WinTh = WinT, *WinTm = WinT + 524288, *WinTl = WinT + 2 * 524288;
  unsigned short* WoutTh = WoutT, *WoutTm = WoutT + 262144, *WoutTl = WoutT + 2 * 262144;

  // ---- fused preprocessing (1 dispatch) ----
  preprocess_kernel<<<dim3(12160), dim3(256), 0, stream>>>(
      x, Wg, Win, Wout, Alog, Xh, Xm, Xl, XGh, XGm, XGl,
      Wgh, Wgm, Wgl, WinTh, WinTm, WinTl, WoutTh, WoutTm, WoutTl, ANEG);

  // ---- gate: K-split x2 (256 blocks) -> PGATE (no combine dispatch; the
  // final combine computes sigmoid((p0+p1)+bg) inline) ----
  gemm_mfma<2><<<dim3(8, 8, 4), dim3(256), 0, stream>>>(
      XGh, XGm, XGl, 0L, 1024,
      Wgh, Wgm, Wgl, (long)1024 * 1024, 1024,
      PGATE, (long)1024 * 1024, 1024, 512);

  for (int s = 0; s < 2; ++s) {
    // GEMM1: UZ = X @ Win[lidx]  (N=512, K=256, full-K, 256 blocks)
    gemm_mfma<1><<<dim3(4, 32, 2), dim3(256), 0, stream>>>(
        Xh, Xm, Xl, (long)4096 * 256, 256,
        WinTh + (long)s * 131072, WinTm + (long)s * 131072, WinTl + (long)s * 131072,
        (long)262144, 256,
        UZ, (long)4096 * 512, 512, 256);

    // fused CONV + GEMM2 + GEMM3 (512 blocks)
    gemm23_kernel<<<dim3(256, 2), dim3(256), 0, stream>>>(
        UZ, Wconv, bconv, Wxp, Wdt, bdt, UC, PROJ, DT, s);

    // chunked selective scan (3 dispatches; 1024-block chunk kernels)
    scan_chunk_kernel<0><<<dim3(2 * 8 * SCAN_NC), dim3(256), 0, stream>>>(
        DT, UC, UZ, PROJ, ANEG, Dskip, HST, DTS, YGh, YGm, YGl, s);
    scan_combine_kernel<<<dim3(256), dim3(256), 0, stream>>>(HST, DTS, ANEG, s);
    scan_chunk_kernel<1><<<dim3(2 * 8 * SCAN_NC), dim3(256), 0, stream>>>(
        DT, UC, UZ, PROJ, ANEG, Dskip, HST, DTS, YGh, YGm, YGl, s);

    // GEMM4: K-split x2 (256 blocks)
    gemm_mfma<2><<<dim3(2, 32, 4), dim3(256), 0, stream>>>(
        YGh, YGm, YGl, (long)4096 * 256, 256,
        WoutTh + (long)s * 65536, WoutTm + (long)s * 65536, WoutTl + (long)s * 65536,
        (long)131072, 256,
        PG, (long)4096 * 256, 256, 128);
    if (s == 0) {
      combine2_kernel<<<dim3(4096, 2), dim3(256), 0, stream>>>(
          PG, (long)4096 * 256, Xh, Xm, Xl, (long)4096 * 256);
    }
    // s1: no combine -- final combine sums the partial planes inline
  }

  combine_kernel<<<dim3(4096), dim3(256), 0, stream>>>(
      PG, (long)4096 * 256, PGATE, bg, alpha, gamma, beta, out);
}